// Round 1
// baseline (2012.672 us; speedup 1.0000x reference)
//
#include <hip/hip_runtime.h>
#include <cstdint>
#include <cstddef>

#define TOKENS 8192
#define HDIM 4096
#define ODIM 4096
#define NEXP 8

using short8  = __attribute__((ext_vector_type(8))) short;
using floatx4 = __attribute__((ext_vector_type(4))) float;

// fp32 -> bf16 with round-to-nearest-even (matches __float2bfloat16)
__device__ __forceinline__ unsigned short f2bf(float f) {
  unsigned u = __float_as_uint(f);
  u = u + 0x7fffu + ((u >> 16) & 1u);
  return (unsigned short)(u >> 16);
}

// async global->LDS, 16B per lane; LDS dest = wave-uniform base + lane*16
__device__ __forceinline__ void async_ld16(const void* g, void* l) {
  __builtin_amdgcn_global_load_lds((const __attribute__((address_space(1))) void*)g,
                                   (__attribute__((address_space(3))) void*)l,
                                   16, 0, 0);
}

// ---------------------------------------------------------------------------
// Kernel 1: gating (fp64 logits -> top-2 -> softmax -> bucket) + x fp32->bf16
// one block per token, 256 threads
// ---------------------------------------------------------------------------
__global__ __launch_bounds__(256) void gate_kernel(
    const float* __restrict__ x, const float* __restrict__ gw,
    unsigned short* __restrict__ xb, int* __restrict__ counts,
    int* __restrict__ lists, float* __restrict__ wts)
{
  const int b = blockIdx.x;
  const int t = threadIdx.x;
  const float4* xr = (const float4*)(x + (size_t)b * HDIM);

  double acc[NEXP];
#pragma unroll
  for (int e = 0; e < NEXP; ++e) acc[e] = 0.0;

#pragma unroll
  for (int i = 0; i < 4; ++i) {
    const int idx = i * 256 + t;           // float4 index within the row
    const float4 v = xr[idx];
    // bf16 conversion (coalesced 8B store)
    ushort4 pack = make_ushort4(f2bf(v.x), f2bf(v.y), f2bf(v.z), f2bf(v.w));
    *(ushort4*)(xb + (size_t)b * HDIM + (size_t)idx * 4) = pack;
    // gating partial dots in fp64 (gate_w row h = 8 contiguous floats)
    const float* g = gw + (size_t)idx * 4 * NEXP;
    const float xs[4] = {v.x, v.y, v.z, v.w};
#pragma unroll
    for (int j = 0; j < 4; ++j) {
      const float4 g0 = *(const float4*)(g + j * NEXP);
      const float4 g1 = *(const float4*)(g + j * NEXP + 4);
      const double xv = (double)xs[j];
      acc[0] += xv * (double)g0.x; acc[1] += xv * (double)g0.y;
      acc[2] += xv * (double)g0.z; acc[3] += xv * (double)g0.w;
      acc[4] += xv * (double)g1.x; acc[5] += xv * (double)g1.y;
      acc[6] += xv * (double)g1.z; acc[7] += xv * (double)g1.w;
    }
  }

  // wave reduce (64 lanes)
#pragma unroll
  for (int off = 32; off > 0; off >>= 1)
#pragma unroll
    for (int e = 0; e < NEXP; ++e)
      acc[e] += __shfl_down(acc[e], off);

  __shared__ double sred[4][NEXP];
  const int w = t >> 6, lane = t & 63;
  if (lane == 0)
#pragma unroll
    for (int e = 0; e < NEXP; ++e) sred[w][e] = acc[e];
  __syncthreads();

  if (t == 0) {
    double lg[NEXP];
#pragma unroll
    for (int e = 0; e < NEXP; ++e)
      lg[e] = sred[0][e] + sred[1][e] + sred[2][e] + sred[3][e];
    // top-2, lower index wins ties (matches jax.lax.top_k)
    int i0 = 0; double v0 = lg[0];
    for (int e = 1; e < NEXP; ++e) if (lg[e] > v0) { v0 = lg[e]; i0 = e; }
    int i1 = -1; double v1 = -1e300;
    for (int e = 0; e < NEXP; ++e) if (e != i0 && lg[e] > v1) { v1 = lg[e]; i1 = e; }
    const double d = exp(v1 - v0);
    const float w0 = (float)(1.0 / (1.0 + d));
    const float w1 = (float)(d / (1.0 + d));
    int p0 = atomicAdd(&counts[i0], 1);
    lists[i0 * TOKENS + p0] = b; wts[i0 * TOKENS + p0] = w0;
    int p1 = atomicAdd(&counts[i1], 1);
    lists[i1 * TOKENS + p1] = b; wts[i1 * TOKENS + p1] = w1;
  }
}

// ---------------------------------------------------------------------------
// Kernel 2: expert_w fp32 [E,H,O] -> bf16 transposed [E,O,H] (B^T for MFMA)
// 64x64 tiles through LDS, both sides coalesced
// ---------------------------------------------------------------------------
__global__ __launch_bounds__(256) void wt_kernel(
    const float* __restrict__ W, unsigned short* __restrict__ wt)
{
  const int e  = blockIdx.z;
  const int h0 = blockIdx.y * 64;
  const int o0 = blockIdx.x * 64;
  const int t  = threadIdx.x;
  __shared__ unsigned short tile[64][68];   // +4 pad breaks bank alias

  const float* Wb = W + (size_t)e * HDIM * ODIM;
  const int r = t >> 4;          // 0..15
  const int c = (t & 15) * 4;    // 0..60
#pragma unroll
  for (int p = 0; p < 4; ++p) {
    const int hr = r + p * 16;
    const float4 v = *(const float4*)(Wb + (size_t)(h0 + hr) * ODIM + o0 + c);
    tile[hr][c]     = f2bf(v.x);
    tile[hr][c + 1] = f2bf(v.y);
    tile[hr][c + 2] = f2bf(v.z);
    tile[hr][c + 3] = f2bf(v.w);
  }
  __syncthreads();

  const int orow = t >> 2;        // 0..63
  const int hc   = (t & 3) * 16;  // 0,16,32,48
  __align__(16) unsigned short outv[16];
#pragma unroll
  for (int i = 0; i < 16; ++i) outv[i] = tile[hc + i][orow];
  unsigned short* dst = wt + ((size_t)e * ODIM + o0 + orow) * HDIM + h0 + hc;
  *(uint4*)(dst)     = *(uint4*)(outv);
  *(uint4*)(dst + 8) = *(uint4*)(outv + 8);
}

// ---------------------------------------------------------------------------
// Kernel 3: grouped gather-GEMM. Per expert: out[tok] += w * (x[tok] @ W_e)
// 128x128 tile, BK=64, mfma_f32_16x16x32_bf16, global_load_lds(16B) staging,
// atomicAdd scatter epilogue (each out element gets exactly 2 adds).
// ---------------------------------------------------------------------------
__global__ __launch_bounds__(256) void moe_gemm(
    const unsigned short* __restrict__ xb, const unsigned short* __restrict__ wt,
    const int* __restrict__ counts, const int* __restrict__ lists,
    const float* __restrict__ wts, float* __restrict__ out)
{
  const int e   = blockIdx.z;
  const int cnt = counts[e];
  const int m0  = blockIdx.y * 128;
  if (m0 >= cnt) return;
  const int n0  = blockIdx.x * 128;

  __shared__ unsigned short As[128 * 64];   // [m][k] row-major
  __shared__ unsigned short Bs[128 * 64];   // [n][k] row-major (B^T tile)
  __shared__ int   rid[128];
  __shared__ float rw[128];

  const int t    = threadIdx.x;
  const int w    = t >> 6;
  const int lane = t & 63;

  if (t < 128) {
    const int r  = m0 + t;
    const int cr = (r < cnt) ? r : (cnt - 1);   // clamp tail rows (discarded at store)
    rid[t] = lists[e * TOKENS + cr];
    rw[t]  = (r < cnt) ? wts[e * TOKENS + r] : 0.0f;
  }
  __syncthreads();

  // staging source pointers: 4 issues/wave for A and B; 8 rows/issue/wave
  const int sub  = lane >> 3;          // row within issue group
  const int koff = (lane & 7) * 8;     // element offset within 128B row
  const unsigned short* aSrc[4];
  const unsigned short* bSrc[4];
#pragma unroll
  for (int i = 0; i < 4; ++i) {
    const int rr = i * 32 + w * 8 + sub;   // 0..127, each exactly once
    aSrc[i] = xb + (size_t)rid[rr] * HDIM + koff;
    bSrc[i] = wt + ((size_t)e * ODIM + n0 + rr) * HDIM + koff;
  }

  floatx4 acc[4][4];
#pragma unroll
  for (int i = 0; i < 4; ++i)
#pragma unroll
    for (int j = 0; j < 4; ++j)
      acc[i][j] = (floatx4){0.f, 0.f, 0.f, 0.f};

  const int wm   = (w >> 1) * 64;
  const int wn   = (w & 1) * 64;
  const int frow = lane & 15;
  const int fk   = (lane >> 4) * 8;

  for (int kt = 0; kt < HDIM / 64; ++kt) {
#pragma unroll
    for (int i = 0; i < 4; ++i) {
      async_ld16(aSrc[i], As + (i * 32 + w * 8) * 64);
      async_ld16(bSrc[i], Bs + (i * 32 + w * 8) * 64);
      aSrc[i] += 64; bSrc[i] += 64;
    }
    __syncthreads();   // drains vmcnt -> LDS tiles complete
#pragma unroll
    for (int kk = 0; kk < 2; ++kk) {
      short8 af[4], bfr[4];
#pragma unroll
      for (int mt = 0; mt < 4; ++mt)
        af[mt] = *(const short8*)(As + (wm + mt * 16 + frow) * 64 + kk * 32 + fk);
#pragma unroll
      for (int nt = 0; nt < 4; ++nt)
        bfr[nt] = *(const short8*)(Bs + (wn + nt * 16 + frow) * 64 + kk * 32 + fk);
#pragma unroll
      for (int mt = 0; mt < 4; ++mt)
#pragma unroll
        for (int nt = 0; nt < 4; ++nt)
          acc[mt][nt] = __builtin_amdgcn_mfma_f32_16x16x32_bf16(af[mt], bfr[nt], acc[mt][nt], 0, 0, 0);
    }
    __syncthreads();
  }

  // epilogue: C/D layout col=lane&15, row=(lane>>4)*4+reg
#pragma unroll
  for (int mt = 0; mt < 4; ++mt) {
    const int lrb = wm + mt * 16 + (lane >> 4) * 4;
#pragma unroll
    for (int r = 0; r < 4; ++r) {
      const int lr = lrb + r;
      if (m0 + lr < cnt) {
        const float wgt = rw[lr];
        float* ob = out + (size_t)rid[lr] * ODIM + n0 + wn + (lane & 15);
#pragma unroll
        for (int nt = 0; nt < 4; ++nt)
          atomicAdd(ob + nt * 16, wgt * acc[mt][nt][r]);
      }
    }
  }
}

// ---------------------------------------------------------------------------
extern "C" void kernel_launch(void* const* d_in, const int* in_sizes, int n_in,
                              void* d_out, int out_size, void* d_ws, size_t ws_size,
                              hipStream_t stream) {
  const float* x  = (const float*)d_in[0];   // [8192,1,4096]
  const float* gw = (const float*)d_in[1];   // [4096,8]
  const float* ew = (const float*)d_in[2];   // [8,4096,4096]
  float* out = (float*)d_out;

  // workspace layout (~337 MB)
  char* ws = (char*)d_ws;
  unsigned short* wt = (unsigned short*)ws;                        // 256 MB bf16 W^T
  size_t off = (size_t)NEXP * HDIM * ODIM * 2;
  unsigned short* xb = (unsigned short*)(ws + off);                // 64 MB bf16 x
  off += (size_t)TOKENS * HDIM * 2;
  int*   counts = (int*)(ws + off); off += 128;
  int*   lists  = (int*)(ws + off); off += (size_t)NEXP * TOKENS * sizeof(int);
  float* wts    = (float*)(ws + off); off += (size_t)NEXP * TOKENS * sizeof(float);
  (void)ws_size; (void)in_sizes; (void)n_in;

  hipMemsetAsync(counts, 0, 128, stream);
  hipMemsetAsync(d_out, 0, (size_t)out_size * sizeof(float), stream);

  gate_kernel<<<TOKENS, 256, 0, stream>>>(x, gw, xb, counts, lists, wts);
  wt_kernel<<<dim3(ODIM / 64, HDIM / 64, NEXP), 256, 0, stream>>>(ew, wt);
  moe_gemm<<<dim3(ODIM / 128, TOKENS / 128, NEXP), 256, 0, stream>>>(xb, wt, counts, lists, wts, out);
}

// Round 2
// 1859.330 us; speedup vs baseline: 1.0825x; 1.0825x over previous
//
#include <hip/hip_runtime.h>
#include <cstdint>
#include <cstddef>

#define TOKENS 8192
#define HDIM 4096
#define ODIM 4096
#define NEXP 8

using short8  = __attribute__((ext_vector_type(8))) short;
using floatx4 = __attribute__((ext_vector_type(4))) float;

// fp32 -> bf16 with round-to-nearest-even
__device__ __forceinline__ unsigned short f2bf(float f) {
  unsigned u = __float_as_uint(f);
  u = u + 0x7fffu + ((u >> 16) & 1u);
  return (unsigned short)(u >> 16);
}

// async global->LDS, 16B per lane; LDS dest = wave-uniform base + lane*16
__device__ __forceinline__ void async_ld16(const void* g, void* l) {
  __builtin_amdgcn_global_load_lds((const __attribute__((address_space(1))) void*)g,
                                   (__attribute__((address_space(3))) void*)l,
                                   16, 0, 0);
}

// ---------------------------------------------------------------------------
// Kernel 1: gating (fp64 logits -> top-2 -> softmax -> bucket) + x fp32->bf16
// ---------------------------------------------------------------------------
__global__ __launch_bounds__(256) void gate_kernel(
    const float* __restrict__ x, const float* __restrict__ gw,
    unsigned short* __restrict__ xb, int* __restrict__ counts,
    int* __restrict__ lists, float* __restrict__ wts)
{
  const int b = blockIdx.x;
  const int t = threadIdx.x;
  const float4* xr = (const float4*)(x + (size_t)b * HDIM);

  double acc[NEXP];
#pragma unroll
  for (int e = 0; e < NEXP; ++e) acc[e] = 0.0;

#pragma unroll
  for (int i = 0; i < 4; ++i) {
    const int idx = i * 256 + t;
    const float4 v = xr[idx];
    ushort4 pack = make_ushort4(f2bf(v.x), f2bf(v.y), f2bf(v.z), f2bf(v.w));
    *(ushort4*)(xb + (size_t)b * HDIM + (size_t)idx * 4) = pack;
    const float* g = gw + (size_t)idx * 4 * NEXP;
    const float xs[4] = {v.x, v.y, v.z, v.w};
#pragma unroll
    for (int j = 0; j < 4; ++j) {
      const float4 g0 = *(const float4*)(g + j * NEXP);
      const float4 g1 = *(const float4*)(g + j * NEXP + 4);
      const double xv = (double)xs[j];
      acc[0] += xv * (double)g0.x; acc[1] += xv * (double)g0.y;
      acc[2] += xv * (double)g0.z; acc[3] += xv * (double)g0.w;
      acc[4] += xv * (double)g1.x; acc[5] += xv * (double)g1.y;
      acc[6] += xv * (double)g1.z; acc[7] += xv * (double)g1.w;
    }
  }

#pragma unroll
  for (int off = 32; off > 0; off >>= 1)
#pragma unroll
    for (int e = 0; e < NEXP; ++e)
      acc[e] += __shfl_down(acc[e], off);

  __shared__ double sred[4][NEXP];
  const int w = t >> 6, lane = t & 63;
  if (lane == 0)
#pragma unroll
    for (int e = 0; e < NEXP; ++e) sred[w][e] = acc[e];
  __syncthreads();

  if (t == 0) {
    double lg[NEXP];
#pragma unroll
    for (int e = 0; e < NEXP; ++e)
      lg[e] = sred[0][e] + sred[1][e] + sred[2][e] + sred[3][e];
    int i0 = 0; double v0 = lg[0];
    for (int e = 1; e < NEXP; ++e) if (lg[e] > v0) { v0 = lg[e]; i0 = e; }
    int i1 = -1; double v1 = -1e300;
    for (int e = 0; e < NEXP; ++e) if (e != i0 && lg[e] > v1) { v1 = lg[e]; i1 = e; }
    const double d = exp(v1 - v0);
    const float w0 = (float)(1.0 / (1.0 + d));
    const float w1 = (float)(d / (1.0 + d));
    int p0 = atomicAdd(&counts[i0], 1);
    lists[i0 * TOKENS + p0] = b; wts[i0 * TOKENS + p0] = w0;
    int p1 = atomicAdd(&counts[i1], 1);
    lists[i1 * TOKENS + p1] = b; wts[i1 * TOKENS + p1] = w1;
  }
}

// ---------------------------------------------------------------------------
// Kernel 2: expert_w fp32 [E,H,O] -> bf16 transposed [E,O,H]  (B^T for MFMA)
// dword-pair packing: LDS tile T[o][h/2] of dwords (lo=bf16(h even), hi=odd)
// stride 33 dwords (odd) -> 2-way banks on writes (free), reads conflict-free
// ---------------------------------------------------------------------------
__global__ __launch_bounds__(256) void wt_kernel(
    const float* __restrict__ W, unsigned short* __restrict__ wt)
{
  const int e  = blockIdx.z;
  const int h0 = blockIdx.y * 64;
  const int o0 = blockIdx.x * 64;
  const int t  = threadIdx.x;
  __shared__ unsigned T[64 * 33];

  const float* Wb = W + (size_t)e * HDIM * ODIM;
  const int rp = t >> 4;       // 0..15  (h-pair)
  const int cq = t & 15;       // o-quad
#pragma unroll
  for (int p = 0; p < 2; ++p) {
    const int h = 2 * rp + 32 * p;
    const float4 v0 = *(const float4*)(Wb + (size_t)(h0 + h) * ODIM + o0 + 4 * cq);
    const float4 v1 = *(const float4*)(Wb + (size_t)(h0 + h + 1) * ODIM + o0 + 4 * cq);
    const float a0[4] = {v0.x, v0.y, v0.z, v0.w};
    const float a1[4] = {v1.x, v1.y, v1.z, v1.w};
#pragma unroll
    for (int j = 0; j < 4; ++j) {
      unsigned d = (unsigned)f2bf(a0[j]) | ((unsigned)f2bf(a1[j]) << 16);
      T[(4 * cq + j) * 33 + (h >> 1)] = d;
    }
  }
  __syncthreads();

#pragma unroll
  for (int p = 0; p < 2; ++p) {
    const int o_l = p * 32 + (t >> 3);
    const int dw  = (t & 7) * 4;
    const unsigned d0 = T[o_l * 33 + dw];
    const unsigned d1 = T[o_l * 33 + dw + 1];
    const unsigned d2 = T[o_l * 33 + dw + 2];
    const unsigned d3 = T[o_l * 33 + dw + 3];
    uint4 pack = make_uint4(d0, d1, d2, d3);
    *(uint4*)(wt + ((size_t)e * ODIM + o0 + o_l) * HDIM + h0 + dw * 2) = pack;
  }
}

// ---------------------------------------------------------------------------
// Kernel 3: grouped gather-GEMM with XOR-swizzled LDS.
// Physical chunk c (16B) of LDS row r holds logical k-chunk (c ^ (r&7)).
// Swizzle applied on the global_load_lds SOURCE address (dest is fixed).
// ---------------------------------------------------------------------------
__global__ __launch_bounds__(256) void moe_gemm(
    const unsigned short* __restrict__ xb, const unsigned short* __restrict__ wt,
    const int* __restrict__ counts, const int* __restrict__ lists,
    const float* __restrict__ wts, float* __restrict__ out)
{
  const int e   = blockIdx.z;
  const int cnt = counts[e];
  const int m0  = blockIdx.y * 128;
  if (m0 >= cnt) return;
  const int n0  = blockIdx.x * 128;

  __shared__ unsigned short As[128 * 64];
  __shared__ unsigned short Bs[128 * 64];
  __shared__ int   rid[128];
  __shared__ float rw[128];

  const int t    = threadIdx.x;
  const int w    = t >> 6;
  const int lane = t & 63;

  if (t < 128) {
    const int r  = m0 + t;
    const int cr = (r < cnt) ? r : (cnt - 1);
    rid[t] = lists[e * TOKENS + cr];
    rw[t]  = (r < cnt) ? wts[e * TOKENS + r] : 0.0f;
  }
  __syncthreads();

  // staging: lane = sub*8 + c; dest chunk c of row (i*32+w*8+sub);
  // source = logical chunk (c ^ sub)  [row&7 == sub since i*32, w*8 ≡ 0 mod 8]
  const int sub  = lane >> 3;
  const int csw  = ((lane & 7) ^ sub) * 8;   // swizzled source element offset
  const unsigned short* aSrc[4];
  const unsigned short* bSrc[4];
#pragma unroll
  for (int i = 0; i < 4; ++i) {
    const int rr = i * 32 + w * 8 + sub;
    aSrc[i] = xb + (size_t)rid[rr] * HDIM + csw;
    bSrc[i] = wt + ((size_t)e * ODIM + n0 + rr) * HDIM + csw;
  }

  floatx4 acc[4][4];
#pragma unroll
  for (int i = 0; i < 4; ++i)
#pragma unroll
    for (int j = 0; j < 4; ++j)
      acc[i][j] = (floatx4){0.f, 0.f, 0.f, 0.f};

  const int wm   = (w >> 1) * 64;
  const int wn   = (w & 1) * 64;
  const int frow = lane & 15;
  const int fk   = lane >> 4;        // k-chunk group 0..3
  const int rsw  = frow & 7;         // row swizzle key for fragment reads

  for (int kt = 0; kt < HDIM / 64; ++kt) {
#pragma unroll
    for (int i = 0; i < 4; ++i) {
      async_ld16(aSrc[i], As + (i * 32 + w * 8) * 64);
      async_ld16(bSrc[i], Bs + (i * 32 + w * 8) * 64);
      aSrc[i] += 64; bSrc[i] += 64;
    }
    __syncthreads();
#pragma unroll
    for (int kk = 0; kk < 2; ++kk) {
      short8 af[4], bfr[4];
#pragma unroll
      for (int mt = 0; mt < 4; ++mt)
        af[mt] = *(const short8*)(As + (wm + mt * 16 + frow) * 64 +
                                  (((kk * 4 + fk) ^ rsw) * 8));
#pragma unroll
      for (int nt = 0; nt < 4; ++nt)
        bfr[nt] = *(const short8*)(Bs + (wn + nt * 16 + frow) * 64 +
                                   (((kk * 4 + fk) ^ rsw) * 8));
#pragma unroll
      for (int mt = 0; mt < 4; ++mt)
#pragma unroll
        for (int nt = 0; nt < 4; ++nt)
          acc[mt][nt] = __builtin_amdgcn_mfma_f32_16x16x32_bf16(af[mt], bfr[nt], acc[mt][nt], 0, 0, 0);
    }
    __syncthreads();
  }

  // epilogue: C/D layout col=lane&15, row=(lane>>4)*4+reg
#pragma unroll
  for (int mt = 0; mt < 4; ++mt) {
    const int lrb = wm + mt * 16 + (lane >> 4) * 4;
#pragma unroll
    for (int r = 0; r < 4; ++r) {
      const int lr = lrb + r;
      if (m0 + lr < cnt) {
        const float wgt = rw[lr];
        float* ob = out + (size_t)rid[lr] * ODIM + n0 + wn + (lane & 15);
#pragma unroll
        for (int nt = 0; nt < 4; ++nt)
          atomicAdd(ob + nt * 16, wgt * acc[mt][nt][r]);
      }
    }
  }
}

// ---------------------------------------------------------------------------
extern "C" void kernel_launch(void* const* d_in, const int* in_sizes, int n_in,
                              void* d_out, int out_size, void* d_ws, size_t ws_size,
                              hipStream_t stream) {
  const float* x  = (const float*)d_in[0];
  const float* gw = (const float*)d_in[1];
  const float* ew = (const float*)d_in[2];
  float* out = (float*)d_out;

  char* ws = (char*)d_ws;
  unsigned short* wt = (unsigned short*)ws;                        // 256 MB bf16 W^T
  size_t off = (size_t)NEXP * HDIM * ODIM * 2;
  unsigned short* xb = (unsigned short*)(ws + off);                // 64 MB bf16 x
  off += (size_t)TOKENS * HDIM * 2;
  int*   counts = (int*)(ws + off); off += 128;
  int*   lists  = (int*)(ws + off); off += (size_t)NEXP * TOKENS * sizeof(int);
  float* wts    = (float*)(ws + off); off += (size_t)NEXP * TOKENS * sizeof(float);
  (void)ws_size; (void)in_sizes; (void)n_in;

  hipMemsetAsync(counts, 0, 128, stream);
  hipMemsetAsync(d_out, 0, (size_t)out_size * sizeof(float), stream);

  gate_kernel<<<TOKENS, 256, 0, stream>>>(x, gw, xb, counts, lists, wts);
  wt_kernel<<<dim3(ODIM / 64, HDIM / 64, NEXP), 256, 0, stream>>>(ew, wt);
  moe_gemm<<<dim3(ODIM / 128, TOKENS / 128, NEXP), 256, 0, stream>>>(xb, wt, counts, lists, wts, out);
}